// Round 21
// baseline (209.082 us; speedup 1.0000x reference)
//
#include <hip/hip_runtime.h>
#include <cmath>

#define NB 4
#define NC 128
#define NH 128
#define NW 128
#define HD 64
#define WD 64
#define NL 4096      // 64*64 positions / patches
#define NPIX 16384   // 128*128 output pixels per batch
#define SM_SCALE 2550.0f
#define CUT 40.0f
#define CUTS 0.216f  // candidate margin in score units
#define MAXENT 8
#define MAXC 256
#define DSTR 136     // Ds LDS row stride (u16), 16B-aligned rows

struct Ent { int l; float p; };

typedef __attribute__((ext_vector_type(4))) float f32x4;
typedef __attribute__((ext_vector_type(8))) short s16x8;

__device__ __forceinline__ unsigned short f2bf(float x) {
  unsigned u = __float_as_uint(x);
  return (unsigned short)((u + 0x7fffu + ((u >> 16) & 1u)) >> 16);
}
__device__ __forceinline__ float bf2f(unsigned short h) {
  return __uint_as_float(((unsigned)h) << 16);
}
__device__ __forceinline__ void gload_lds16(const void* g, void* l) {
  __builtin_amdgcn_global_load_lds(
      (const __attribute__((address_space(1))) void*)g,
      (__attribute__((address_space(3))) void*)l, 16, 0, 0);
}

// ---------- prep ----------
__global__ void k_prep(const float* __restrict__ f, const float* __restrict__ b,
                       float* __restrict__ fd, float* __restrict__ bd) {
  int i = blockIdx.x * blockDim.x + threadIdx.x;
  if (i >= NB*NC*HD*WD) return;
  int x = i & 63, y = (i >> 6) & 63, c = (i >> 12) & 127, bb = i >> 19;
  int src = ((bb*NC + c)*NH + 2*y)*NW + 2*x;
  fd[i] = f[src];
  bd[i] = b[src];
}

__global__ void k_sq(const float* __restrict__ bd, double* __restrict__ sq) {
  int i = blockIdx.x * blockDim.x + threadIdx.x;
  if (i >= NB*HD*WD) return;
  int x = i & 63, y = (i >> 6) & 63, bb = i >> 12;
  double s = 0.0;
  const float* p = bd + (size_t)bb*NC*HD*WD + y*WD + x;
  for (int c = 0; c < NC; ++c) {
    double v = (double)p[(size_t)c*HD*WD];
    s += v*v;
  }
  sq[i] = s;
}

// norm, masked reciprocal (NaN when masked), zero-count
__global__ void k_normmm(const double* __restrict__ sq, const float* __restrict__ mask,
                         float* __restrict__ norm, float* __restrict__ rnm,
                         int* __restrict__ zb) {
  int i = blockIdx.x * blockDim.x + threadIdx.x;
  if (i >= NB*NL) return;
  int pw = i & 63, ph = (i >> 6) & 63, bb = i >> 12;
  double s = 0.0;
  for (int dh = -1; dh <= 1; ++dh) {
    int y = ph + dh; if ((unsigned)y >= 64u) continue;
    for (int dw = -1; dw <= 1; ++dw) {
      int x = pw + dw; if ((unsigned)x >= 64u) continue;
      s += sq[(bb*HD + y)*WD + x];
    }
  }
  float nv = (float)sqrt(s);
  norm[i] = nv;
  float ms = 0.f;
  const float* mb = mask + (size_t)bb*512*512;
  for (int dh = -1; dh <= 1; ++dh) {
    int y = ph + dh; if ((unsigned)y >= 64u) continue;
    for (int dw = -1; dw <= 1; ++dw) {
      int x = pw + dw; if ((unsigned)x >= 64u) continue;
      ms += mb[(y*8)*512 + x*8];
    }
  }
  bool unmasked = (ms == 0.f);
  rnm[i] = unmasked ? (1.f / fmaxf(nv, 1e-4f)) : __uint_as_float(0x7fc00000u);
  if (!unmasked) atomicAdd(&zb[bb], 1);
}

// ---------- transpose b to pixel-major b_t[bb][pix][c] (for gather) ----------
__global__ __launch_bounds__(256) void k_btrans(const float* __restrict__ b,
                                                float* __restrict__ bt) {
  __shared__ float tile[32][33];
  int bb = blockIdx.z;
  int c0 = blockIdx.y * 32;
  int p0 = blockIdx.x * 32;
  int tx = threadIdx.x & 31, ty = threadIdx.x >> 5;
  const float* bp = b + (size_t)bb*NC*NPIX;
  #pragma unroll
  for (int r = 0; r < 32; r += 8)
    tile[r + ty][tx] = bp[(size_t)(c0 + r + ty)*NPIX + p0 + tx];
  __syncthreads();
  float* btp = bt + (size_t)bb*NPIX*NC;
  #pragma unroll
  for (int r = 0; r < 32; r += 8)
    btp[(size_t)(p0 + r + ty)*NC + c0 + tx] = tile[tx][r + ty];
}

// ---------- transpose fd,bd to pixel-major: bf16 (GEMM) + fp32 (rescore) ----------
__global__ __launch_bounds__(256) void k_fbtrans(const float* __restrict__ fd,
    const float* __restrict__ bd, unsigned short* __restrict__ fdt,
    unsigned short* __restrict__ bdt, float* __restrict__ fdp,
    float* __restrict__ bdp) {
  __shared__ float tf[32][33], tb[32][33];
  int bb = blockIdx.z;
  int c0 = blockIdx.y * 32;
  int p0 = blockIdx.x * 32;
  int tx = threadIdx.x & 31, ty = threadIdx.x >> 5;
  const float* fp = fd + (size_t)bb*NC*NL;
  const float* bp = bd + (size_t)bb*NC*NL;
  #pragma unroll
  for (int r = 0; r < 32; r += 8) {
    tf[r + ty][tx] = fp[(size_t)(c0 + r + ty)*NL + p0 + tx];
    tb[r + ty][tx] = bp[(size_t)(c0 + r + ty)*NL + p0 + tx];
  }
  __syncthreads();
  #pragma unroll
  for (int r = 0; r < 32; r += 8) {
    float fv = tf[tx][r + ty];
    float bv = tb[tx][r + ty];
    size_t idx = ((size_t)bb*NL + p0 + r + ty)*NC + c0 + tx;
    fdt[idx] = f2bf(fv);
    bdt[idx] = f2bf(bv);
    fdp[idx] = fv;
    bdp[idx] = bv;
  }
}

// ---------- pixel-dot GEMM with fused horizontal stencil: writes E directly ----------
__global__ __launch_bounds__(256) void k_gemmE(
    const unsigned short* __restrict__ A, const unsigned short* __restrict__ B,
    unsigned short* __restrict__ Eall, size_t eStride, int bbFixed) {
  __shared__ __align__(16) unsigned short Smem[128*DSTR];  // 34.8 KB; As/Bs union Ds
  unsigned short* As = Smem;            // 128*32 u16
  unsigned short* Bs = Smem + 128*32;
  unsigned short* Ds = Smem;
  int bb = (bbFixed >= 0) ? bbFixed : blockIdx.z;
  const unsigned short* Abase = A + (size_t)bb*NL*NC;
  const unsigned short* Bbase = B + (size_t)bb*NL*NC;
  unsigned short* E = Eall + (size_t)(bbFixed >= 0 ? 0 : bb) * eStride;
  int t = threadIdx.x;
  int w = t >> 6, l = t & 63;
  int by = blockIdx.y, bx = blockIdx.x;
  int wr = w >> 1, wc = w & 1;
  f32x4 acc[4][4] = {};
  int aoff[4], boff[4];
  #pragma unroll
  for (int m = 0; m < 4; ++m) {
    aoff[m] = ((wr*64 + m*16 + (l & 15)) * 32 + ((l >> 4) * 8)) * 2;
    boff[m] = ((wc*64 + m*16 + (l & 15)) * 32 + ((l >> 4) * 8)) * 2;
  }
  const char* Ab = (const char*)Abase;
  const char* Bb = (const char*)Bbase;
  char* AsB = (char*)As;
  char* BsB = (char*)Bs;
  int off = (w*2) * 1024 + l * 16;
  int r0i = off >> 6, cb0 = off & 63;
  int off1 = off + 1024;
  int r1i = off1 >> 6, cb1 = off1 & 63;
  for (int k0 = 0; k0 < 128; k0 += 32) {
    gload_lds16(Ab + ((size_t)(by*128 + r0i) * 128 + k0) * 2 + cb0, AsB + (w*2+0)*1024);
    gload_lds16(Ab + ((size_t)(by*128 + r1i) * 128 + k0) * 2 + cb1, AsB + (w*2+1)*1024);
    gload_lds16(Bb + ((size_t)(bx*128 + r0i) * 128 + k0) * 2 + cb0, BsB + (w*2+0)*1024);
    gload_lds16(Bb + ((size_t)(bx*128 + r1i) * 128 + k0) * 2 + cb1, BsB + (w*2+1)*1024);
    __syncthreads();
    s16x8 af[4], bf[4];
    #pragma unroll
    for (int m = 0; m < 4; ++m) af[m] = *(const s16x8*)(AsB + aoff[m]);
    #pragma unroll
    for (int n = 0; n < 4; ++n) bf[n] = *(const s16x8*)(BsB + boff[n]);
    #pragma unroll
    for (int m = 0; m < 4; ++m)
      #pragma unroll
      for (int n = 0; n < 4; ++n)
        acc[m][n] = __builtin_amdgcn_mfma_f32_16x16x32_bf16(af[m], bf[n], acc[m][n], 0, 0, 0);
    __syncthreads();
  }
  int cr = l >> 4;
  int cc = l & 15;
  #pragma unroll
  for (int n = 0; n < 4; ++n) {
    int col = wc*64 + n*16 + cc;
    #pragma unroll
    for (int m = 0; m < 4; ++m) {
      int row = wr*64 + m*16 + cr*4;
      #pragma unroll
      for (int j = 0; j < 4; ++j)
        Ds[(row + j)*DSTR + col] = f2bf(acc[m][n][j]);
    }
  }
  __syncthreads();
  #pragma unroll
  for (int rr = 0; rr < 8; ++rr) {
    int r = (t >> 4) + rr*16;
    int cb = (t & 15) * 8;
    bool okm = (r & 63) > 0;
    bool okp = (r & 63) < 63;
    const unsigned short* rowc = Ds + r*DSTR;
    uint4 cen = *(const uint4*)(rowc + cb);
    uint4 bm4 = okm ? *(const uint4*)(rowc - DSTR + cb) : make_uint4(0,0,0,0);
    uint4 bp4 = okp ? *(const uint4*)(rowc + DSTR + cb) : make_uint4(0,0,0,0);
    unsigned amw = (okm && (cb & 63) != 0)  ? *(const unsigned*)(rowc - DSTR + cb - 2) : 0u;
    unsigned cpx = (okp && (cb & 63) != 56) ? *(const unsigned*)(rowc + DSTR + cb + 8) : 0u;
    unsigned b0u[4] = {cen.x, cen.y, cen.z, cen.w};
    unsigned bmu[4] = {bm4.x, bm4.y, bm4.z, bm4.w};
    unsigned bpu[4] = {bp4.x, bp4.y, bp4.z, bp4.w};
    unsigned sm[4], sp[4];
    sm[0] = (amw >> 16)    | (bmu[0] << 16);
    sm[1] = (bmu[0] >> 16) | (bmu[1] << 16);
    sm[2] = (bmu[1] >> 16) | (bmu[2] << 16);
    sm[3] = (bmu[2] >> 16) | (bmu[3] << 16);
    sp[0] = (bpu[0] >> 16) | (bpu[1] << 16);
    sp[1] = (bpu[1] >> 16) | (bpu[2] << 16);
    sp[2] = (bpu[2] >> 16) | (bpu[3] << 16);
    sp[3] = (bpu[3] >> 16) | (cpx << 16);
    unsigned eo[4];
    #pragma unroll
    for (int k = 0; k < 4; ++k) {
      int lx0 = (cb + 2*k) & 63;
      float v0 = (okm && lx0 > 0) ? bf2f((unsigned short)(sm[k] & 0xffffu)) : 0.f;
      v0 += bf2f((unsigned short)(b0u[k] & 0xffffu));
      v0 += (okp && lx0 < 63) ? bf2f((unsigned short)(sp[k] & 0xffffu)) : 0.f;
      int lx1 = (cb + 2*k + 1) & 63;
      float v1 = (okm && lx1 > 0) ? bf2f((unsigned short)(sm[k] >> 16)) : 0.f;
      v1 += bf2f((unsigned short)(b0u[k] >> 16));
      v1 += (okp && lx1 < 63) ? bf2f((unsigned short)(sp[k] >> 16)) : 0.f;
      eo[k] = (unsigned)f2bf(v0) | ((unsigned)f2bf(v1) << 16);
    }
    uint4 outv; outv.x = eo[0]; outv.y = eo[1]; outv.z = eo[2]; outv.w = eo[3];
    *(uint4*)(E + (size_t)(by*128 + r) * NL + bx*128 + cb) = outv;
  }
}

// ---------- rescore v6: block stages 6 E tap-rows via global_load_lds ----------
// block = (g,px): 4 waves own rows p=(g*4+w)*64+px; taps shared through LDS.
__global__ __launch_bounds__(256) void k_rescore6(const unsigned short* __restrict__ Eall,
    size_t eStride, const float* __restrict__ rnm, const float* __restrict__ fdp,
    const float* __restrict__ bdp, const float* __restrict__ nrm,
    const int* __restrict__ zb, int* __restrict__ cnt, Ent* __restrict__ ent,
    float* __restrict__ ooff, int bbFixed) {
  __shared__ __align__(16) unsigned short Erows[6*4096];  // 48 KB; cs aliases after scan
  __shared__ int cl_s[4][MAXC];                            // 4 KB
  __shared__ int cnt_s[4];
  int bb = (bbFixed >= 0) ? bbFixed : blockIdx.y;
  const unsigned short* E = Eall + (size_t)(bbFixed >= 0 ? 0 : bb) * eStride;
  int t = threadIdx.x;
  int w = t >> 6, lane = t & 63;
  int bi = blockIdx.x;
  int g = bi >> 6, px = bi & 63;
  int py = g*4 + w;
  int p = py*64 + px;
  int ihp = py, iwp = px;
  int* cl = cl_s[w];
  const float* fdpb = fdp + (size_t)bb*NL*NC;
  const float* bdpb = bdp + (size_t)bb*NL*NC;
  const float* rb = rnm + bb*NL;
  const float* nb = nrm + bb*NL;
  if (lane == 0) cnt_s[w] = 0;

  // stage 6 tap rows (py = g*4-1 .. g*4+4), each 8192 B = 8 wave-chunks of 1024 B
  #pragma unroll
  for (int i = 0; i < 6; ++i) {
    int rpy = g*4 - 1 + i;
    if ((unsigned)rpy < 64u) {
      const char* src = (const char*)(E + (size_t)(rpy*64 + px)*NL);
      char* dst = (char*)Erows + i*8192;
      gload_lds16(src + w*1024 + lane*16, dst + w*1024);
      gload_lds16(src + 4096 + w*1024 + lane*16, dst + 4096 + w*1024);
    }
  }

  // fpat in registers: lane owns channels {2*lane, 2*lane+1} for each of 9 taps
  float fpat[18];
  #pragma unroll
  for (int r = 0; r < 9; ++r) {
    int y = ihp + r/3 - 1, x = iwp + (r % 3) - 1;
    bool ok = ((unsigned)y < 64u) && ((unsigned)x < 64u);
    float2 v = ok ? *(const float2*)(fdpb + (size_t)(y*WD + x)*NC + lane*2)
                  : make_float2(0.f, 0.f);
    fpat[2*r]     = v.x;
    fpat[2*r + 1] = v.y;
  }
  __syncthreads();   // staged rows visible

  // single pass over LDS rows: compute s, track max, keep packed bf16 in registers
  const unsigned short* Ec = Erows + (w+1)*4096;
  const unsigned short* Eu = Erows + (w+0)*4096;
  const unsigned short* Ed = Erows + (w+2)*4096;
  unsigned spk[8][4];
  float mx = -3e38f;
  #pragma unroll
  for (int j = 0; j < 8; ++j) {
    int cb = j*512 + lane*8;
    int ly = cb >> 6;
    bool okm = (py > 0) && (ly > 0);
    bool okp = (py < 63) && (ly < 63);
    uint4 e0 = *(const uint4*)(Ec + cb);
    uint4 em = *(const uint4*)(okm ? (Eu + cb - 64) : (Ec + cb));
    uint4 ep = *(const uint4*)(okp ? (Ed + cb + 64) : (Ec + cb));
    float4 r0 = *(const float4*)(rb + cb);
    float4 r1 = *(const float4*)(rb + cb + 4);
    unsigned e0u[4] = {e0.x,e0.y,e0.z,e0.w};
    unsigned emu[4] = {em.x,em.y,em.z,em.w};
    unsigned epu[4] = {ep.x,ep.y,ep.z,ep.w};
    float rr8[8] = {r0.x,r0.y,r0.z,r0.w,r1.x,r1.y,r1.z,r1.w};
    #pragma unroll
    for (int k = 0; k < 4; ++k) {
      float v0 = okm ? bf2f((unsigned short)(emu[k] & 0xffffu)) : 0.f;
      v0 += bf2f((unsigned short)(e0u[k] & 0xffffu));
      v0 += okp ? bf2f((unsigned short)(epu[k] & 0xffffu)) : 0.f;
      float v1 = okm ? bf2f((unsigned short)(emu[k] >> 16)) : 0.f;
      v1 += bf2f((unsigned short)(e0u[k] >> 16));
      v1 += okp ? bf2f((unsigned short)(epu[k] >> 16)) : 0.f;
      float s0 = v0 * rr8[2*k];          // NaN when masked
      float s1 = v1 * rr8[2*k+1];
      mx = fmaxf(mx, s0);                // fmaxf ignores NaN
      mx = fmaxf(mx, s1);
      spk[j][k] = (unsigned)f2bf(s0) | ((unsigned)f2bf(s1) << 16);
    }
  }
  #pragma unroll
  for (int o = 32; o > 0; o >>= 1) mx = fmaxf(mx, __shfl_xor(mx, o, 64));
  float thr = mx - CUTS;

  // collect candidates from registers (NaN >= thr is false)
  #pragma unroll
  for (int j = 0; j < 8; ++j) {
    int cb = j*512 + lane*8;
    #pragma unroll
    for (int k = 0; k < 4; ++k) {
      float s0 = bf2f((unsigned short)(spk[j][k] & 0xffffu));
      float s1 = bf2f((unsigned short)(spk[j][k] >> 16));
      if (s0 >= thr) {
        int slot = atomicAdd(&cnt_s[w], 1);
        if (slot < MAXC) cl[slot] = cb + 2*k;
      }
      if (s1 >= thr) {
        int slot = atomicAdd(&cnt_s[w], 1);
        if (slot < MAXC) cl[slot] = cb + 2*k + 1;
      }
    }
  }
  int nc = cnt_s[w];           // wave-synchronous: atomics complete within wave
  nc = __shfl(nc, 0, 64);
  nc = nc < MAXC ? nc : MAXC;
  if (lane == 0 && nc > 1) {   // deterministic order: sort candidates by l
    for (int a = 1; a < nc; ++a) {
      int v = cl[a]; int q = a - 1;
      while (q >= 0 && cl[q] > v) { cl[q+1] = cl[q]; --q; }
      cl[q+1] = v;
    }
  }
  __syncthreads();             // Erows dead; reuse its space for cs
  float* cs = (float*)Erows + w*MAXC;

  // exact fp32 dot per candidate: lane = channel pair (coalesced float2)
  for (int a = 0; a < nc; ++a) {
    int lidx = cl[a];
    int ph = lidx >> 6, pw = lidx & 63;
    float sum = 0.f;
    #pragma unroll
    for (int r = 0; r < 9; ++r) {
      int y = ph + r/3 - 1, x = pw + (r % 3) - 1;
      bool ok = ((unsigned)y < 64u) && ((unsigned)x < 64u);
      const float* brow = bdpb + (size_t)(y*WD + x)*NC;
      float2 bv = ok ? *(const float2*)(brow + lane*2) : make_float2(0.f, 0.f);
      sum = fmaf(fpat[2*r],     bv.x, sum);
      sum = fmaf(fpat[2*r + 1], bv.y, sum);
    }
    #pragma unroll
    for (int o = 32; o > 0; o >>= 1) sum += __shfl_xor(sum, o, 64);
    if (lane == 0) cs[a] = sum / fmaxf(nb[lidx], 1e-4f);
  }
  if (lane == 0) {
    float smax = -3e38f; int sidx = 0x7fffffff;
    for (int a = 0; a < nc; ++a)
      if (cs[a] > smax) { smax = cs[a]; sidx = cl[a]; }   // sorted by l
    int Z = zb[bb];
    size_t base = (size_t)(bb*NL + p) * MAXENT;
    if (nc == 0) {
      cnt[bb*NL + p] = 0;
      ooff[((bb*2 + 0)*HD + ihp)*WD + iwp] = (float)(0 - ihp);
      ooff[((bb*2 + 1)*HD + ihp)*WD + iwp] = (float)(0 - iwp);
    } else {
      float xm = smax * SM_SCALE;
      if (Z > 0) xm = fmaxf(xm, 0.f);
      float den = 0.f;
      for (int a = 0; a < nc; ++a) {
        float d = cs[a] * SM_SCALE - xm;
        if (d > -CUT) den += expf(d);
      }
      if (Z > 0 && -xm > -CUT) den += (float)Z * expf(-xm);
      int n = 0;
      for (int a = 0; a < nc && n < MAXENT; ++a) {
        float d = cs[a] * SM_SCALE - xm;
        if (d > -CUT) { ent[base + n].l = cl[a]; ent[base + n].p = expf(d) / den; ++n; }
      }
      cnt[bb*NL + p] = n;
      ooff[((bb*2 + 0)*HD + ihp)*WD + iwp] = (float)((sidx >> 6) - ihp);
      ooff[((bb*2 + 1)*HD + ihp)*WD + iwp] = (float)((sidx & 63) - iwp);
    }
  }
}

// ---------- gather v6: parallel plan (32 threads = pixel x position), no concat ----------
__global__ __launch_bounds__(256) void k_gather6(const float* __restrict__ bt,
    const int* __restrict__ cnt, const Ent* __restrict__ ent,
    float* __restrict__ yout) {
  __shared__ float sm[8][132];
  __shared__ int   qcnt[8][4];
  __shared__ int   qoff[8][4][MAXENT];
  __shared__ float qwt[8][4][MAXENT];
  int bb = blockIdx.y;
  int pixbase = blockIdx.x * 8;
  int t = threadIdx.x;
  // plan: thread (pl, q) handles input position q=(a*2+d) of pixel pl
  if (t < 32) {
    int pl = t >> 2, q = t & 3;
    int pix = pixbase + pl;
    int oh = pix >> 7, ow = pix & 127;
    int ih = ((oh - 1) >> 1) + (q >> 1);
    int iw = ((ow - 1) >> 1) + (q & 1);
    int n = 0;
    if ((unsigned)ih < 64u && (unsigned)iw < 64u) {
      int pidx = bb*NL + ih*WD + iw;
      int nn = cnt[pidx];
      const Ent* ep = ent + (size_t)pidx*MAXENT;
      for (int j = 0; j < nn; ++j) {
        Ent e = ep[j];
        int ph = e.l >> 6, pw = e.l & 63;
        int yy = oh + 2*(ph - ih);
        int xx = ow + 2*(pw - iw);
        if ((unsigned)yy < 128u && (unsigned)xx < 128u) {
          qoff[pl][q][n] = yy*NW + xx;
          qwt[pl][q][n] = e.p;
          ++n;
        }
      }
    }
    qcnt[pl][q] = n;
  }
  __syncthreads();
  int g = t & 31, pl = t >> 5;
  int c0 = g * 4;
  const float* btb = bt + (size_t)bb*NPIX*NC;
  float ax = 0.f, ay = 0.f, az = 0.f, aw = 0.f;
  // iterate (q asc, j asc): same contribution order as the old concatenated list
  #pragma unroll
  for (int q = 0; q < 4; ++q) {
    int nq = qcnt[pl][q];
    for (int j = 0; j < nq; ++j) {
      int off = qoff[pl][q][j];
      float wv = qwt[pl][q][j];
      float4 v = *(const float4*)(btb + (size_t)off*NC + c0);
      ax = fmaf(wv, v.x, ax); ay = fmaf(wv, v.y, ay);
      az = fmaf(wv, v.z, az); aw = fmaf(wv, v.w, aw);
    }
  }
  sm[pl][c0+0] = ax; sm[pl][c0+1] = ay; sm[pl][c0+2] = az; sm[pl][c0+3] = aw;
  __syncthreads();
  #pragma unroll
  for (int k = 0; k < 4; ++k) {
    int c = (t >> 3) + 32*k;
    int i = t & 7;
    yout[((size_t)bb*NC + c)*NPIX + pixbase + i] = sm[i][c] * 0.25f;
  }
}

extern "C" void kernel_launch(void* const* d_in, const int* in_sizes, int n_in,
                              void* d_out, int out_size, void* d_ws, size_t ws_size,
                              hipStream_t stream) {
  const float* f = (const float*)d_in[0];
  const float* b = (const float*)d_in[1];
  const float* mask = (const float*)d_in[2];
  float* out = (float*)d_out;

  char* w = (char*)d_ws;
  float* fd   = (float*)w;  w += (size_t)NB*NC*HD*WD*4;
  float* bd   = (float*)w;  w += (size_t)NB*NC*HD*WD*4;
  double* sq  = (double*)w; w += (size_t)NB*HD*WD*8;
  float* norm = (float*)w;  w += (size_t)NB*NL*4;
  float* rnm  = (float*)w;  w += (size_t)NB*NL*4;
  int* cnt    = (int*)w;    w += (size_t)NB*NL*4;
  Ent* ent    = (Ent*)w;    w += (size_t)NB*NL*MAXENT*sizeof(Ent);
  unsigned short* fdt = (unsigned short*)w; w += (size_t)NB*NL*NC*2;
  unsigned short* bdt = (unsigned short*)w; w += (size_t)NB*NL*NC*2;
  float* fdp  = (float*)w;  w += (size_t)NB*NL*NC*4;
  float* bdp  = (float*)w;  w += (size_t)NB*NL*NC*4;
  int* zb     = (int*)w;    w += 64;

  size_t eBytes = (size_t)NL*NL*2;          // one batch of E (33.55 MB)
  size_t usedSoFar = (size_t)(w - (char*)d_ws);
  bool batched = (ws_size >= usedSoFar + (size_t)NB*eBytes);

  unsigned short* E = (unsigned short*)w;   // bt aliases E (E consumed before btrans)
  float* bt = (float*)w;

  int n1 = NB*NC*HD*WD;
  k_prep<<<(n1+255)/256, 256, 0, stream>>>(f, b, fd, bd);
  k_sq<<<(NB*HD*WD+255)/256, 256, 0, stream>>>(bd, sq);
  hipMemsetAsync(zb, 0, 64, stream);
  k_normmm<<<(NB*NL+255)/256, 256, 0, stream>>>(sq, mask, norm, rnm, zb);
  k_fbtrans<<<dim3(NL/32, NC/32, NB), 256, 0, stream>>>(fd, bd, fdt, bdt, fdp, bdp);

  float* ooff = out + (size_t)NB*NC*NH*NW;
  if (batched) {
    k_gemmE<<<dim3(32, 32, NB), 256, 0, stream>>>(fdt, bdt, E, (size_t)NL*NL, -1);
    k_rescore6<<<dim3(NL/4, NB), 256, 0, stream>>>(E, (size_t)NL*NL, rnm, fdp, bdp,
                                                   norm, zb, cnt, ent, ooff, -1);
  } else {
    for (int bb = 0; bb < NB; ++bb) {
      k_gemmE<<<dim3(32, 32), 256, 0, stream>>>(fdt, bdt, E, 0, bb);
      k_rescore6<<<dim3(NL/4), 256, 0, stream>>>(E, 0, rnm, fdp, bdp,
                                                 norm, zb, cnt, ent, ooff, bb);
    }
  }
  k_btrans<<<dim3(NPIX/32, NC/32, NB), 256, 0, stream>>>(b, bt);
  k_gather6<<<dim3(NPIX/8, NB), 256, 0, stream>>>(bt, cnt, ent, out);
}

// Round 22
// 189.057 us; speedup vs baseline: 1.1059x; 1.1059x over previous
//
#include <hip/hip_runtime.h>
#include <cmath>

#define NB 4
#define NC 128
#define NH 128
#define NW 128
#define HD 64
#define WD 64
#define NL 4096      // 64*64 positions / patches
#define NPIX 16384   // 128*128 output pixels per batch
#define SM_SCALE 2550.0f
#define CUT 40.0f
#define CUTS 0.216f  // candidate margin in score units
#define MAXENT 8
#define MAXC 256
#define DSTR 136     // Ds LDS row stride (u16), 16B-aligned rows

struct Ent { int l; float p; };

typedef __attribute__((ext_vector_type(4))) float f32x4;
typedef __attribute__((ext_vector_type(8))) short s16x8;

__device__ __forceinline__ unsigned short f2bf(float x) {
  unsigned u = __float_as_uint(x);
  return (unsigned short)((u + 0x7fffu + ((u >> 16) & 1u)) >> 16);
}
__device__ __forceinline__ float bf2f(unsigned short h) {
  return __uint_as_float(((unsigned)h) << 16);
}
__device__ __forceinline__ void gload_lds16(const void* g, void* l) {
  __builtin_amdgcn_global_load_lds(
      (const __attribute__((address_space(1))) void*)g,
      (__attribute__((address_space(3))) void*)l, 16, 0, 0);
}

// ---------- prep ----------
__global__ void k_prep(const float* __restrict__ f, const float* __restrict__ b,
                       float* __restrict__ fd, float* __restrict__ bd) {
  int i = blockIdx.x * blockDim.x + threadIdx.x;
  if (i >= NB*NC*HD*WD) return;
  int x = i & 63, y = (i >> 6) & 63, c = (i >> 12) & 127, bb = i >> 19;
  int src = ((bb*NC + c)*NH + 2*y)*NW + 2*x;
  fd[i] = f[src];
  bd[i] = b[src];
}

__global__ void k_sq(const float* __restrict__ bd, double* __restrict__ sq) {
  int i = blockIdx.x * blockDim.x + threadIdx.x;
  if (i >= NB*HD*WD) return;
  int x = i & 63, y = (i >> 6) & 63, bb = i >> 12;
  double s = 0.0;
  const float* p = bd + (size_t)bb*NC*HD*WD + y*WD + x;
  for (int c = 0; c < NC; ++c) {
    double v = (double)p[(size_t)c*HD*WD];
    s += v*v;
  }
  sq[i] = s;
}

// norm, masked reciprocal (NaN when masked), zero-count
__global__ void k_normmm(const double* __restrict__ sq, const float* __restrict__ mask,
                         float* __restrict__ norm, float* __restrict__ rnm,
                         int* __restrict__ zb) {
  int i = blockIdx.x * blockDim.x + threadIdx.x;
  if (i >= NB*NL) return;
  int pw = i & 63, ph = (i >> 6) & 63, bb = i >> 12;
  double s = 0.0;
  for (int dh = -1; dh <= 1; ++dh) {
    int y = ph + dh; if ((unsigned)y >= 64u) continue;
    for (int dw = -1; dw <= 1; ++dw) {
      int x = pw + dw; if ((unsigned)x >= 64u) continue;
      s += sq[(bb*HD + y)*WD + x];
    }
  }
  float nv = (float)sqrt(s);
  norm[i] = nv;
  float ms = 0.f;
  const float* mb = mask + (size_t)bb*512*512;
  for (int dh = -1; dh <= 1; ++dh) {
    int y = ph + dh; if ((unsigned)y >= 64u) continue;
    for (int dw = -1; dw <= 1; ++dw) {
      int x = pw + dw; if ((unsigned)x >= 64u) continue;
      ms += mb[(y*8)*512 + x*8];
    }
  }
  bool unmasked = (ms == 0.f);
  rnm[i] = unmasked ? (1.f / fmaxf(nv, 1e-4f)) : __uint_as_float(0x7fc00000u);
  if (!unmasked) atomicAdd(&zb[bb], 1);
}

// ---------- transpose b to pixel-major b_t[bb][pix][c] (for gather) ----------
__global__ __launch_bounds__(256) void k_btrans(const float* __restrict__ b,
                                                float* __restrict__ bt) {
  __shared__ float tile[32][33];
  int bb = blockIdx.z;
  int c0 = blockIdx.y * 32;
  int p0 = blockIdx.x * 32;
  int tx = threadIdx.x & 31, ty = threadIdx.x >> 5;
  const float* bp = b + (size_t)bb*NC*NPIX;
  #pragma unroll
  for (int r = 0; r < 32; r += 8)
    tile[r + ty][tx] = bp[(size_t)(c0 + r + ty)*NPIX + p0 + tx];
  __syncthreads();
  float* btp = bt + (size_t)bb*NPIX*NC;
  #pragma unroll
  for (int r = 0; r < 32; r += 8)
    btp[(size_t)(p0 + r + ty)*NC + c0 + tx] = tile[tx][r + ty];
}

// ---------- transpose fd,bd to pixel-major: bf16 (GEMM) + fp32 (rescore) ----------
__global__ __launch_bounds__(256) void k_fbtrans(const float* __restrict__ fd,
    const float* __restrict__ bd, unsigned short* __restrict__ fdt,
    unsigned short* __restrict__ bdt, float* __restrict__ fdp,
    float* __restrict__ bdp) {
  __shared__ float tf[32][33], tb[32][33];
  int bb = blockIdx.z;
  int c0 = blockIdx.y * 32;
  int p0 = blockIdx.x * 32;
  int tx = threadIdx.x & 31, ty = threadIdx.x >> 5;
  const float* fp = fd + (size_t)bb*NC*NL;
  const float* bp = bd + (size_t)bb*NC*NL;
  #pragma unroll
  for (int r = 0; r < 32; r += 8) {
    tf[r + ty][tx] = fp[(size_t)(c0 + r + ty)*NL + p0 + tx];
    tb[r + ty][tx] = bp[(size_t)(c0 + r + ty)*NL + p0 + tx];
  }
  __syncthreads();
  #pragma unroll
  for (int r = 0; r < 32; r += 8) {
    float fv = tf[tx][r + ty];
    float bv = tb[tx][r + ty];
    size_t idx = ((size_t)bb*NL + p0 + r + ty)*NC + c0 + tx;
    fdt[idx] = f2bf(fv);
    bdt[idx] = f2bf(bv);
    fdp[idx] = fv;
    bdp[idx] = bv;
  }
}

// ---------- pixel-dot GEMM with fused horizontal stencil: writes E directly ----------
__global__ __launch_bounds__(256) void k_gemmE(
    const unsigned short* __restrict__ A, const unsigned short* __restrict__ B,
    unsigned short* __restrict__ Eall, size_t eStride, int bbFixed) {
  __shared__ __align__(16) unsigned short Smem[128*DSTR];  // 34.8 KB; As/Bs union Ds
  unsigned short* As = Smem;            // 128*32 u16
  unsigned short* Bs = Smem + 128*32;
  unsigned short* Ds = Smem;
  int bb = (bbFixed >= 0) ? bbFixed : blockIdx.z;
  const unsigned short* Abase = A + (size_t)bb*NL*NC;
  const unsigned short* Bbase = B + (size_t)bb*NL*NC;
  unsigned short* E = Eall + (size_t)(bbFixed >= 0 ? 0 : bb) * eStride;
  int t = threadIdx.x;
  int w = t >> 6, l = t & 63;
  int by = blockIdx.y, bx = blockIdx.x;
  int wr = w >> 1, wc = w & 1;
  f32x4 acc[4][4] = {};
  int aoff[4], boff[4];
  #pragma unroll
  for (int m = 0; m < 4; ++m) {
    aoff[m] = ((wr*64 + m*16 + (l & 15)) * 32 + ((l >> 4) * 8)) * 2;
    boff[m] = ((wc*64 + m*16 + (l & 15)) * 32 + ((l >> 4) * 8)) * 2;
  }
  const char* Ab = (const char*)Abase;
  const char* Bb = (const char*)Bbase;
  char* AsB = (char*)As;
  char* BsB = (char*)Bs;
  int off = (w*2) * 1024 + l * 16;
  int r0i = off >> 6, cb0 = off & 63;
  int off1 = off + 1024;
  int r1i = off1 >> 6, cb1 = off1 & 63;
  for (int k0 = 0; k0 < 128; k0 += 32) {
    gload_lds16(Ab + ((size_t)(by*128 + r0i) * 128 + k0) * 2 + cb0, AsB + (w*2+0)*1024);
    gload_lds16(Ab + ((size_t)(by*128 + r1i) * 128 + k0) * 2 + cb1, AsB + (w*2+1)*1024);
    gload_lds16(Bb + ((size_t)(bx*128 + r0i) * 128 + k0) * 2 + cb0, BsB + (w*2+0)*1024);
    gload_lds16(Bb + ((size_t)(bx*128 + r1i) * 128 + k0) * 2 + cb1, BsB + (w*2+1)*1024);
    __syncthreads();
    s16x8 af[4], bf[4];
    #pragma unroll
    for (int m = 0; m < 4; ++m) af[m] = *(const s16x8*)(AsB + aoff[m]);
    #pragma unroll
    for (int n = 0; n < 4; ++n) bf[n] = *(const s16x8*)(BsB + boff[n]);
    #pragma unroll
    for (int m = 0; m < 4; ++m)
      #pragma unroll
      for (int n = 0; n < 4; ++n)
        acc[m][n] = __builtin_amdgcn_mfma_f32_16x16x32_bf16(af[m], bf[n], acc[m][n], 0, 0, 0);
    __syncthreads();
  }
  int cr = l >> 4;
  int cc = l & 15;
  #pragma unroll
  for (int n = 0; n < 4; ++n) {
    int col = wc*64 + n*16 + cc;
    #pragma unroll
    for (int m = 0; m < 4; ++m) {
      int row = wr*64 + m*16 + cr*4;
      #pragma unroll
      for (int j = 0; j < 4; ++j)
        Ds[(row + j)*DSTR + col] = f2bf(acc[m][n][j]);
    }
  }
  __syncthreads();
  #pragma unroll
  for (int rr = 0; rr < 8; ++rr) {
    int r = (t >> 4) + rr*16;
    int cb = (t & 15) * 8;
    bool okm = (r & 63) > 0;
    bool okp = (r & 63) < 63;
    const unsigned short* rowc = Ds + r*DSTR;
    uint4 cen = *(const uint4*)(rowc + cb);
    uint4 bm4 = okm ? *(const uint4*)(rowc - DSTR + cb) : make_uint4(0,0,0,0);
    uint4 bp4 = okp ? *(const uint4*)(rowc + DSTR + cb) : make_uint4(0,0,0,0);
    unsigned amw = (okm && (cb & 63) != 0)  ? *(const unsigned*)(rowc - DSTR + cb - 2) : 0u;
    unsigned cpx = (okp && (cb & 63) != 56) ? *(const unsigned*)(rowc + DSTR + cb + 8) : 0u;
    unsigned b0u[4] = {cen.x, cen.y, cen.z, cen.w};
    unsigned bmu[4] = {bm4.x, bm4.y, bm4.z, bm4.w};
    unsigned bpu[4] = {bp4.x, bp4.y, bp4.z, bp4.w};
    unsigned sm[4], sp[4];
    sm[0] = (amw >> 16)    | (bmu[0] << 16);
    sm[1] = (bmu[0] >> 16) | (bmu[1] << 16);
    sm[2] = (bmu[1] >> 16) | (bmu[2] << 16);
    sm[3] = (bmu[2] >> 16) | (bmu[3] << 16);
    sp[0] = (bpu[0] >> 16) | (bpu[1] << 16);
    sp[1] = (bpu[1] >> 16) | (bpu[2] << 16);
    sp[2] = (bpu[2] >> 16) | (bpu[3] << 16);
    sp[3] = (bpu[3] >> 16) | (cpx << 16);
    unsigned eo[4];
    #pragma unroll
    for (int k = 0; k < 4; ++k) {
      int lx0 = (cb + 2*k) & 63;
      float v0 = (okm && lx0 > 0) ? bf2f((unsigned short)(sm[k] & 0xffffu)) : 0.f;
      v0 += bf2f((unsigned short)(b0u[k] & 0xffffu));
      v0 += (okp && lx0 < 63) ? bf2f((unsigned short)(sp[k] & 0xffffu)) : 0.f;
      int lx1 = (cb + 2*k + 1) & 63;
      float v1 = (okm && lx1 > 0) ? bf2f((unsigned short)(sm[k] >> 16)) : 0.f;
      v1 += bf2f((unsigned short)(b0u[k] >> 16));
      v1 += (okp && lx1 < 63) ? bf2f((unsigned short)(sp[k] >> 16)) : 0.f;
      eo[k] = (unsigned)f2bf(v0) | ((unsigned)f2bf(v1) << 16);
    }
    uint4 outv; outv.x = eo[0]; outv.y = eo[1]; outv.z = eo[2]; outv.w = eo[3];
    *(uint4*)(E + (size_t)(by*128 + r) * NL + bx*128 + cb) = outv;
  }
}

// ---------- wave-per-row rescore (round-14/16 form): fpat in registers ----------
__global__ __launch_bounds__(256) void k_rescore5(const unsigned short* __restrict__ Eall,
    size_t eStride, const float* __restrict__ rnm, const float* __restrict__ fdp,
    const float* __restrict__ bdp, const float* __restrict__ nrm,
    const int* __restrict__ zb, int* __restrict__ cnt, Ent* __restrict__ ent,
    float* __restrict__ ooff, int bbFixed) {
  __shared__ int   cl_s[4][MAXC];
  __shared__ float cs_s[4][MAXC];
  __shared__ int   cnt_s[4];
  int bb = (bbFixed >= 0) ? bbFixed : blockIdx.y;
  const unsigned short* E = Eall + (size_t)(bbFixed >= 0 ? 0 : bb) * eStride;
  int t = threadIdx.x;
  int w = t >> 6, lane = t & 63;
  int p = blockIdx.x * 4 + w;
  int py = p >> 6;
  int ihp = py, iwp = p & 63;
  int* cl = cl_s[w];
  float* cs = cs_s[w];
  const float* fdpb = fdp + (size_t)bb*NL*NC;
  const float* bdpb = bdp + (size_t)bb*NL*NC;
  const float* rb = rnm + bb*NL;
  const float* nb = nrm + bb*NL;
  if (lane == 0) cnt_s[w] = 0;

  // fpat in registers: lane owns channels {2*lane, 2*lane+1} for each of 9 taps
  float fpat[18];
  #pragma unroll
  for (int r = 0; r < 9; ++r) {
    int y = ihp + r/3 - 1, x = iwp + (r % 3) - 1;
    bool ok = ((unsigned)y < 64u) && ((unsigned)x < 64u);
    float2 v = ok ? *(const float2*)(fdpb + (size_t)(y*WD + x)*NC + lane*2)
                  : make_float2(0.f, 0.f);
    fpat[2*r]     = v.x;
    fpat[2*r + 1] = v.y;
  }

  // single pass: compute s (fp32), track max, keep packed-bf16 copies in registers
  unsigned spk[8][4];
  float mx = -3e38f;
  #pragma unroll
  for (int j = 0; j < 8; ++j) {
    int cb = j*512 + lane*8;
    int ly = cb >> 6;
    bool okm = (py > 0) && (ly > 0);
    bool okp = (py < 63) && (ly < 63);
    size_t a0 = (size_t)p*NL + cb;
    uint4 e0 = *(const uint4*)(E + a0);
    uint4 em = *(const uint4*)(E + (okm ? ((size_t)(p-64)*NL + cb - 64) : a0));
    uint4 ep = *(const uint4*)(E + (okp ? ((size_t)(p+64)*NL + cb + 64) : a0));
    float4 r0 = *(const float4*)(rb + cb);
    float4 r1 = *(const float4*)(rb + cb + 4);
    unsigned e0u[4] = {e0.x,e0.y,e0.z,e0.w};
    unsigned emu[4] = {em.x,em.y,em.z,em.w};
    unsigned epu[4] = {ep.x,ep.y,ep.z,ep.w};
    float rr8[8] = {r0.x,r0.y,r0.z,r0.w,r1.x,r1.y,r1.z,r1.w};
    #pragma unroll
    for (int k = 0; k < 4; ++k) {
      float v0 = okm ? bf2f((unsigned short)(emu[k] & 0xffffu)) : 0.f;
      v0 += bf2f((unsigned short)(e0u[k] & 0xffffu));
      v0 += okp ? bf2f((unsigned short)(epu[k] & 0xffffu)) : 0.f;
      float v1 = okm ? bf2f((unsigned short)(emu[k] >> 16)) : 0.f;
      v1 += bf2f((unsigned short)(e0u[k] >> 16));
      v1 += okp ? bf2f((unsigned short)(epu[k] >> 16)) : 0.f;
      float s0 = v0 * rr8[2*k];          // NaN when masked
      float s1 = v1 * rr8[2*k+1];
      mx = fmaxf(mx, s0);                // fmaxf ignores NaN
      mx = fmaxf(mx, s1);
      spk[j][k] = (unsigned)f2bf(s0) | ((unsigned)f2bf(s1) << 16);
    }
  }
  #pragma unroll
  for (int o = 32; o > 0; o >>= 1) mx = fmaxf(mx, __shfl_xor(mx, o, 64));
  float thr = mx - CUTS;

  // collect candidates from registers (NaN >= thr is false)
  #pragma unroll
  for (int j = 0; j < 8; ++j) {
    int cb = j*512 + lane*8;
    #pragma unroll
    for (int k = 0; k < 4; ++k) {
      float s0 = bf2f((unsigned short)(spk[j][k] & 0xffffu));
      float s1 = bf2f((unsigned short)(spk[j][k] >> 16));
      if (s0 >= thr) {
        int slot = atomicAdd(&cnt_s[w], 1);
        if (slot < MAXC) cl[slot] = cb + 2*k;
      }
      if (s1 >= thr) {
        int slot = atomicAdd(&cnt_s[w], 1);
        if (slot < MAXC) cl[slot] = cb + 2*k + 1;
      }
    }
  }
  int nc = cnt_s[w];           // wave-synchronous: atomics complete within wave
  nc = __shfl(nc, 0, 64);
  nc = nc < MAXC ? nc : MAXC;
  if (lane == 0 && nc > 1) {   // deterministic order: sort candidates by l
    for (int a = 1; a < nc; ++a) {
      int v = cl[a]; int q = a - 1;
      while (q >= 0 && cl[q] > v) { cl[q+1] = cl[q]; --q; }
      cl[q+1] = v;
    }
  }
  // exact fp32 dot per candidate: lane = channel pair (coalesced float2)
  for (int a = 0; a < nc; ++a) {
    int lidx = cl[a];
    int ph = lidx >> 6, pw = lidx & 63;
    float sum = 0.f;
    #pragma unroll
    for (int r = 0; r < 9; ++r) {
      int y = ph + r/3 - 1, x = pw + (r % 3) - 1;
      bool ok = ((unsigned)y < 64u) && ((unsigned)x < 64u);
      const float* brow = bdpb + (size_t)(y*WD + x)*NC;
      float2 bv = ok ? *(const float2*)(brow + lane*2) : make_float2(0.f, 0.f);
      sum = fmaf(fpat[2*r],     bv.x, sum);
      sum = fmaf(fpat[2*r + 1], bv.y, sum);
    }
    #pragma unroll
    for (int o = 32; o > 0; o >>= 1) sum += __shfl_xor(sum, o, 64);
    if (lane == 0) cs[a] = sum / fmaxf(nb[lidx], 1e-4f);
  }
  if (lane == 0) {
    float smax = -3e38f; int sidx = 0x7fffffff;
    for (int a = 0; a < nc; ++a)
      if (cs[a] > smax) { smax = cs[a]; sidx = cl[a]; }   // sorted by l
    int Z = zb[bb];
    size_t base = (size_t)(bb*NL + p) * MAXENT;
    if (nc == 0) {
      cnt[bb*NL + p] = 0;
      ooff[((bb*2 + 0)*HD + ihp)*WD + iwp] = (float)(0 - ihp);
      ooff[((bb*2 + 1)*HD + ihp)*WD + iwp] = (float)(0 - iwp);
    } else {
      float xm = smax * SM_SCALE;
      if (Z > 0) xm = fmaxf(xm, 0.f);
      float den = 0.f;
      for (int a = 0; a < nc; ++a) {
        float d = cs[a] * SM_SCALE - xm;
        if (d > -CUT) den += expf(d);
      }
      if (Z > 0 && -xm > -CUT) den += (float)Z * expf(-xm);
      int n = 0;
      for (int a = 0; a < nc && n < MAXENT; ++a) {
        float d = cs[a] * SM_SCALE - xm;
        if (d > -CUT) { ent[base + n].l = cl[a]; ent[base + n].p = expf(d) / den; ++n; }
      }
      cnt[bb*NL + p] = n;
      ooff[((bb*2 + 0)*HD + ihp)*WD + iwp] = (float)((sidx >> 6) - ihp);
      ooff[((bb*2 + 1)*HD + ihp)*WD + iwp] = (float)((sidx & 63) - iwp);
    }
  }
}

// ---------- gather v6: parallel plan (32 threads = pixel x position), no concat ----------
__global__ __launch_bounds__(256) void k_gather6(const float* __restrict__ bt,
    const int* __restrict__ cnt, const Ent* __restrict__ ent,
    float* __restrict__ yout) {
  __shared__ float sm[8][132];
  __shared__ int   qcnt[8][4];
  __shared__ int   qoff[8][4][MAXENT];
  __shared__ float qwt[8][4][MAXENT];
  int bb = blockIdx.y;
  int pixbase = blockIdx.x * 8;
  int t = threadIdx.x;
  // plan: thread (pl, q) handles input position q=(a*2+d) of pixel pl
  if (t < 32) {
    int pl = t >> 2, q = t & 3;
    int pix = pixbase + pl;
    int oh = pix >> 7, ow = pix & 127;
    int ih = ((oh - 1) >> 1) + (q >> 1);
    int iw = ((ow - 1) >> 1) + (q & 1);
    int n = 0;
    if ((unsigned)ih < 64u && (unsigned)iw < 64u) {
      int pidx = bb*NL + ih*WD + iw;
      int nn = cnt[pidx];
      const Ent* ep = ent + (size_t)pidx*MAXENT;
      for (int j = 0; j < nn; ++j) {
        Ent e = ep[j];
        int ph = e.l >> 6, pw = e.l & 63;
        int yy = oh + 2*(ph - ih);
        int xx = ow + 2*(pw - iw);
        if ((unsigned)yy < 128u && (unsigned)xx < 128u) {
          qoff[pl][q][n] = yy*NW + xx;
          qwt[pl][q][n] = e.p;
          ++n;
        }
      }
    }
    qcnt[pl][q] = n;
  }
  __syncthreads();
  int g = t & 31, pl = t >> 5;
  int c0 = g * 4;
  const float* btb = bt + (size_t)bb*NPIX*NC;
  float ax = 0.f, ay = 0.f, az = 0.f, aw = 0.f;
  // iterate (q asc, j asc): same contribution order as the old concatenated list
  #pragma unroll
  for (int q = 0; q < 4; ++q) {
    int nq = qcnt[pl][q];
    for (int j = 0; j < nq; ++j) {
      int off = qoff[pl][q][j];
      float wv = qwt[pl][q][j];
      float4 v = *(const float4*)(btb + (size_t)off*NC + c0);
      ax = fmaf(wv, v.x, ax); ay = fmaf(wv, v.y, ay);
      az = fmaf(wv, v.z, az); aw = fmaf(wv, v.w, aw);
    }
  }
  sm[pl][c0+0] = ax; sm[pl][c0+1] = ay; sm[pl][c0+2] = az; sm[pl][c0+3] = aw;
  __syncthreads();
  #pragma unroll
  for (int k = 0; k < 4; ++k) {
    int c = (t >> 3) + 32*k;
    int i = t & 7;
    yout[((size_t)bb*NC + c)*NPIX + pixbase + i] = sm[i][c] * 0.25f;
  }
}

extern "C" void kernel_launch(void* const* d_in, const int* in_sizes, int n_in,
                              void* d_out, int out_size, void* d_ws, size_t ws_size,
                              hipStream_t stream) {
  const float* f = (const float*)d_in[0];
  const float* b = (const float*)d_in[1];
  const float* mask = (const float*)d_in[2];
  float* out = (float*)d_out;

  char* w = (char*)d_ws;
  float* fd   = (float*)w;  w += (size_t)NB*NC*HD*WD*4;
  float* bd   = (float*)w;  w += (size_t)NB*NC*HD*WD*4;
  double* sq  = (double*)w; w += (size_t)NB*HD*WD*8;
  float* norm = (float*)w;  w += (size_t)NB*NL*4;
  float* rnm  = (float*)w;  w += (size_t)NB*NL*4;
  int* cnt    = (int*)w;    w += (size_t)NB*NL*4;
  Ent* ent    = (Ent*)w;    w += (size_t)NB*NL*MAXENT*sizeof(Ent);
  unsigned short* fdt = (unsigned short*)w; w += (size_t)NB*NL*NC*2;
  unsigned short* bdt = (unsigned short*)w; w += (size_t)NB*NL*NC*2;
  float* fdp  = (float*)w;  w += (size_t)NB*NL*NC*4;
  float* bdp  = (float*)w;  w += (size_t)NB*NL*NC*4;
  int* zb     = (int*)w;    w += 64;

  size_t eBytes = (size_t)NL*NL*2;          // one batch of E (33.55 MB)
  size_t usedSoFar = (size_t)(w - (char*)d_ws);
  bool batched = (ws_size >= usedSoFar + (size_t)NB*eBytes);

  unsigned short* E = (unsigned short*)w;   // bt aliases E (E consumed before btrans)
  float* bt = (float*)w;

  int n1 = NB*NC*HD*WD;
  k_prep<<<(n1+255)/256, 256, 0, stream>>>(f, b, fd, bd);
  k_sq<<<(NB*HD*WD+255)/256, 256, 0, stream>>>(bd, sq);
  hipMemsetAsync(zb, 0, 64, stream);
  k_normmm<<<(NB*NL+255)/256, 256, 0, stream>>>(sq, mask, norm, rnm, zb);
  k_fbtrans<<<dim3(NL/32, NC/32, NB), 256, 0, stream>>>(fd, bd, fdt, bdt, fdp, bdp);

  float* ooff = out + (size_t)NB*NC*NH*NW;
  if (batched) {
    k_gemmE<<<dim3(32, 32, NB), 256, 0, stream>>>(fdt, bdt, E, (size_t)NL*NL, -1);
    k_rescore5<<<dim3(NL/4, NB), 256, 0, stream>>>(E, (size_t)NL*NL, rnm, fdp, bdp,
                                                   norm, zb, cnt, ent, ooff, -1);
  } else {
    for (int bb = 0; bb < NB; ++bb) {
      k_gemmE<<<dim3(32, 32), 256, 0, stream>>>(fdt, bdt, E, 0, bb);
      k_rescore5<<<dim3(NL/4), 256, 0, stream>>>(E, 0, rnm, fdp, bdp,
                                                 norm, zb, cnt, ent, ooff, bb);
    }
  }
  k_btrans<<<dim3(NPIX/32, NC/32, NB), 256, 0, stream>>>(b, bt);
  k_gather6<<<dim3(NPIX/8, NB), 256, 0, stream>>>(bt, cnt, ent, out);
}